// Round 12
// baseline (228.467 us; speedup 1.0000x reference)
//
#include <hip/hip_runtime.h>
#include <math.h>

#define C 256
#define S 4096
#define NH 8
#define NSG 32        // ksweep2 s-groups per bn (128 s each) = Mp partial groups
#define NSTRIP 16     // 256-s strips per bn = LP/ZP granularity
#define EPS 1e-5f
#define SCALE 0.17677669529663687f   // 1/sqrt(32)

#define PTS2 136      // ksweep2 ptT LDS row stride (ushorts)

// workspace layout (float offsets)
#define OFF_GW  0                  // 64*256*8 = 131072 ([bn][c][h])
#define OFF_G   131072             // 512
#define OFF_BC  131584             // 512
#define OFF_PTT 132096             // 64*8*4096 ushorts = 1048576 floats
#define OFF_LP  1180672            // 512*16 = 8192
#define OFF_ZP  1188864            // 8192
#define OFF_MP  1197056            // 32*64*256*8 = 4194304

typedef __attribute__((ext_vector_type(8))) short short8;
typedef __attribute__((ext_vector_type(4))) float f32x4;

__device__ __forceinline__ unsigned int bf_pack(float a, float b) {
    unsigned int ua = (__builtin_bit_cast(unsigned int, a) + 0x8000u) >> 16;
    unsigned int ub = (__builtin_bit_cast(unsigned int, b) + 0x8000u) & 0xffff0000u;
    return ua | ub;
}

// ---------------------------------------------------------------------------
// K1: LN(mask_tokens) -> q -> fold q into Wk. gw stored TRANSPOSED [c][h].
// ---------------------------------------------------------------------------
__global__ __launch_bounds__(256) void k1_prep(
    const float* __restrict__ mt, const float* __restrict__ ln_t_w, const float* __restrict__ ln_t_b,
    const float* __restrict__ ln_p_w, const float* __restrict__ ln_p_b,
    const float* __restrict__ Wq, const float* __restrict__ bq,
    const float* __restrict__ Wk, const float* __restrict__ bk,
    float* __restrict__ gw, float* __restrict__ Gv, float* __restrict__ Bc)
{
    int bn  = blockIdx.x;
    int tid = threadIdx.x;
    int wid = tid >> 6, lane = tid & 63;
    __shared__ float nt[C];
    __shared__ float qv[C];
    __shared__ float wks[NH][C];
    __shared__ float red[8];

    float x  = mt[bn * C + tid];
    float s1 = x, s2 = x * x;
    #pragma unroll
    for (int off = 32; off; off >>= 1) {
        s1 += __shfl_xor(s1, off);
        s2 += __shfl_xor(s2, off);
    }
    if (lane == 0) { red[wid] = s1; red[4 + wid] = s2; }
    __syncthreads();
    float mu   = (red[0] + red[1] + red[2] + red[3]) * (1.0f / C);
    float msq  = (red[4] + red[5] + red[6] + red[7]) * (1.0f / C);
    float rstd = rsqrtf(msq - mu * mu + EPS);
    nt[tid] = (x - mu) * rstd * ln_t_w[tid] + ln_t_b[tid];
    __syncthreads();

    {   // q[j=tid] = nt . Wq[j,:] + bq[j]
        float acc = bq[tid];
        const float* wrow = Wq + (size_t)tid * C;
        #pragma unroll 8
        for (int c = 0; c < C; ++c) acc += nt[c] * wrow[c];
        qv[tid] = acc;
    }
    __syncthreads();

    int c = tid;
    #pragma unroll
    for (int h = 0; h < NH; ++h) {
        float a = 0.f;
        #pragma unroll 4
        for (int d = 0; d < 32; ++d) a += qv[h * 32 + d] * Wk[(size_t)(h * 32 + d) * C + c];
        wks[h][c] = a * SCALE;
    }
    __syncthreads();

    for (int i = tid; i < C * NH; i += 256) {
        int cc = i >> 3, h = i & 7;
        gw[(size_t)bn * C * NH + i] = ln_p_w[cc] * wks[h][cc];
    }

    {
        int h = tid >> 5, l32 = tid & 31;
        float g = 0.f, bs = 0.f;
        #pragma unroll
        for (int cc = l32; cc < C; cc += 32) {
            float w = wks[h][cc];
            g  += ln_p_w[cc] * w;
            bs += ln_p_b[cc] * w;
        }
        float qb = qv[h * 32 + l32] * bk[h * 32 + l32];
        #pragma unroll
        for (int off = 16; off; off >>= 1) {
            g  += __shfl_xor(g, off);
            bs += __shfl_xor(bs, off);
            qb += __shfl_xor(qb, off);
        }
        if (l32 == 0) {
            Gv[bn * NH + h] = g;
            Bc[bn * NH + h] = bs + qb * SCALE;
        }
    }
}

// ---------------------------------------------------------------------------
// KSWEEP1 v4 (contiguity-first): grid 256 = 64 bn x 4 sgroups(1024 s); 4 waves;
// wave owns a 256-s strip x ALL 256 c; lane owns 4 CONSECUTIVE s.
// Every pe load = 64 lanes x float4 = 1 KB single contiguous segment
// (full DRAM-page bursts). Stats complete in-lane (no shuffles until LP/ZP).
// g from 8 KB LDS tile (2 broadcast b128/c). m=0 softmax (validated r4-r11).
// ---------------------------------------------------------------------------
__global__ __launch_bounds__(256) void ksweep1(
    const float* __restrict__ pe, const float* __restrict__ gw,
    const float* __restrict__ Gv, const float* __restrict__ Bc,
    unsigned short* __restrict__ ptg, float* __restrict__ LP, float* __restrict__ ZP)
{
    int blk = blockIdx.x;                    // 256
    int swz = (blk & 7) * 32 + (blk >> 3);   // XCD-contiguous chunks
    int bn  = swz >> 2;
    int sgp = swz & 3;
    int tid = threadIdx.x;
    int w = tid >> 6, lane = tid & 63;
    int b = bn >> 3, n = bn & 7;
    const float* xb = pe + ((size_t)(n * 8 + b)) * C * S;

    __shared__ float gwt[C * NH];   // 8 KB
    {
        const float4* src = reinterpret_cast<const float4*>(gw + (size_t)bn * C * NH);
        float4* dst = reinterpret_cast<float4*>(gwt);
        for (int i = tid; i < C * NH / 4; i += 256) dst[i] = src[i];
    }
    __syncthreads();

    int s0 = sgp * 1024 + w * 256;           // wave's 256-s strip
    const float* xq = xb + s0 + lane * 4;    // lane's 4 consecutive s

    float sum[4] = {0.f,0.f,0.f,0.f}, sq[4] = {0.f,0.f,0.f,0.f};
    float A[4][NH];
    #pragma unroll
    for (int e = 0; e < 4; ++e)
        #pragma unroll
        for (int h = 0; h < NH; ++h) A[e][h] = 0.f;

    #pragma unroll 8
    for (int cc = 0; cc < C; ++cc) {
        float4 xv = *reinterpret_cast<const float4*>(xq + (size_t)cc * S);
        float4 g0 = *reinterpret_cast<const float4*>(&gwt[cc * 8]);
        float4 g1 = *reinterpret_cast<const float4*>(&gwt[cc * 8 + 4]);
        float xe[4] = {xv.x, xv.y, xv.z, xv.w};
        #pragma unroll
        for (int e = 0; e < 4; ++e) {
            float xx = xe[e];
            sum[e] += xx;
            sq[e]  += xx * xx;
            A[e][0] += g0.x * xx; A[e][1] += g0.y * xx;
            A[e][2] += g0.z * xx; A[e][3] += g0.w * xx;
            A[e][4] += g1.x * xx; A[e][5] += g1.y * xx;
            A[e][6] += g1.z * xx; A[e][7] += g1.w * xx;
        }
    }

    float rs4[4], mur4[4];
    #pragma unroll
    for (int e = 0; e < 4; ++e) {
        float mu  = sum[e] * (1.f / C);
        float var = sq[e] * (1.f / C) - mu * mu;
        rs4[e]  = rsqrtf(var + EPS);
        mur4[e] = mu * rs4[e];
    }

    float lp[NH], zp[NH];
    #pragma unroll
    for (int h = 0; h < NH; ++h) {
        float Gh = Gv[bn * NH + h], Bh = Bc[bn * NH + h];
        float pr[4];
        float l = 0.f, zz = 0.f;
        #pragma unroll
        for (int e = 0; e < 4; ++e) {
            float p = __expf(rs4[e] * A[e][h] - mur4[e] * Gh + Bh);
            l  += p;
            zz += p * mur4[e];
            pr[e] = p * rs4[e];
        }
        lp[h] = l; zp[h] = zz;
        uint2 pk;
        pk.x = bf_pack(pr[0], pr[1]);
        pk.y = bf_pack(pr[2], pr[3]);
        *reinterpret_cast<uint2*>(ptg + ((size_t)(bn * NH + h)) * S + s0 + lane * 4) = pk;
    }

    // strip (=wave) reduce over 64 lanes
    #pragma unroll
    for (int h = 0; h < NH; ++h) {
        float l = lp[h], zz = zp[h];
        #pragma unroll
        for (int off = 32; off; off >>= 1) {
            l  += __shfl_xor(l,  off);
            zz += __shfl_xor(zz, off);
        }
        if (lane == 0) {
            int strip = sgp * 4 + w;
            LP[(size_t)(bn * NH + h) * NSTRIP + strip] = l;
            ZP[(size_t)(bn * NH + h) * NSTRIP + strip] = zz;
        }
    }
}

// ---------------------------------------------------------------------------
// KSWEEP2 v3: grid 2048 = 64 bn x 32 sg(128 s). ptT staged to LDS (4.4 KB);
// A from x (L2/L3-hot after ksweep1); M[c][h] via mfma_f32_16x16x32_bf16;
// acc stored DIRECTLY to Mp (no LDS stage, no second barrier).
// ---------------------------------------------------------------------------
__global__ __launch_bounds__(256) void ksweep2(
    const float* __restrict__ pe, const unsigned short* __restrict__ ptg,
    float* __restrict__ Mp)
{
    int blk = blockIdx.x;                     // 2048
    int swz = (blk & 7) * 256 + (blk >> 3);
    int bn  = swz >> 5;
    int sg  = swz & 31;
    int tid = threadIdx.x;
    int w   = tid >> 6, lane = tid & 63;
    int b = bn >> 3, n = bn & 7;
    const float* xb = pe + ((size_t)(n * 8 + b)) * C * S;
    int sgbase = sg * 128;

    __shared__ unsigned short ptT[16 * PTS2];   // 4352 B

    // stage ptT rows 0-7 from global (coalesced uints), rows 8-15 zero
    for (int i = tid; i < 16 * 64; i += 256) {
        int h = i >> 6, si = (i & 63) * 2;
        unsigned int v = 0;
        if (h < NH)
            v = *reinterpret_cast<const unsigned int*>(
                    ptg + ((size_t)(bn * NH + h)) * S + sgbase + si);
        *reinterpret_cast<unsigned int*>(&ptT[h * PTS2 + si]) = v;
    }
    __syncthreads();

    {
        int mrow = lane & 15;     // A row within tile; D col (= h)
        int kgrp = lane >> 4;     // k block (8 k each)
        float* mp = Mp + (((size_t)sg * 64 + bn) * C) * NH;
        #pragma unroll
        for (int ct = 0; ct < 4; ++ct) {
            int ctile = w * 4 + ct;
            int crow  = ctile * 16 + mrow;
            const float* arow = xb + (size_t)crow * S + sgbase + kgrp * 8;
            f32x4 acc = {0.f, 0.f, 0.f, 0.f};
            #pragma unroll
            for (int kc = 0; kc < 4; ++kc) {
                float4 a0 = *reinterpret_cast<const float4*>(arow + kc * 32);
                float4 a1 = *reinterpret_cast<const float4*>(arow + kc * 32 + 4);
                uint4 ap;
                ap.x = bf_pack(a0.x, a0.y);
                ap.y = bf_pack(a0.z, a0.w);
                ap.z = bf_pack(a1.x, a1.y);
                ap.w = bf_pack(a1.z, a1.w);
                short8 af = __builtin_bit_cast(short8, ap);
                uint4 bp = *reinterpret_cast<const uint4*>(&ptT[mrow * PTS2 + kc * 32 + kgrp * 8]);
                short8 bfv = __builtin_bit_cast(short8, bp);
                acc = __builtin_amdgcn_mfma_f32_16x16x32_bf16(af, bfv, acc, 0, 0, 0);
            }
            if (mrow < NH) {
                #pragma unroll
                for (int r = 0; r < 4; ++r) {
                    int cl = ctile * 16 + kgrp * 4 + r;
                    mp[cl * NH + mrow] = acc[r];
                }
            }
        }
    }
}

// ---------------------------------------------------------------------------
// K5 v2 (merged k3+kfold+k5): per bn: IL/z from strips -> Mp fold -> wei (LDS)
// -> ctx -> Wo -> residual -> MLP -> out. Per-thread serial-K GEMVs.
// ---------------------------------------------------------------------------
__global__ __launch_bounds__(256) void k5_out(
    const float* __restrict__ mt, const float* __restrict__ Mp,
    const float* __restrict__ LP, const float* __restrict__ ZP,
    const float* __restrict__ lpw, const float* __restrict__ lpb,
    const float* __restrict__ Wv, const float* __restrict__ bv,
    const float* __restrict__ Wo, const float* __restrict__ bo,
    const float* __restrict__ W1, const float* __restrict__ b1,
    const float* __restrict__ W2, const float* __restrict__ b2,
    float* __restrict__ out)
{
    int bn  = blockIdx.x;
    int tid = threadIdx.x;
    __shared__ float ilz[2 * NH];   // il[8], z[8]
    __shared__ float wei[NH * C];   // [h][c]
    __shared__ float ctxs[C];
    __shared__ float upds[C];
    __shared__ float hid[2 * C];

    if (tid < NH) {
        float L = 0.f, Z = 0.f;
        #pragma unroll
        for (int j = 0; j < NSTRIP; ++j) {
            L += LP[(size_t)(bn * NH + tid) * NSTRIP + j];
            Z += ZP[(size_t)(bn * NH + tid) * NSTRIP + j];
        }
        float inv = 1.f / L;
        ilz[tid]      = inv;
        ilz[NH + tid] = Z * inv;
    }
    __syncthreads();

    // fold 32 Mp partials -> wei[h][c]
    for (int v = tid; v < 512; v += 256) {
        int i = v * 4;
        float4 m4 = {0.f, 0.f, 0.f, 0.f};
        #pragma unroll 8
        for (int sg2 = 0; sg2 < NSG; ++sg2) {
            float4 t = *reinterpret_cast<const float4*>(Mp + ((size_t)sg2 * 64 + bn) * (C * NH) + i);
            m4.x += t.x; m4.y += t.y; m4.z += t.z; m4.w += t.w;
        }
        int c = i >> 3, h0 = i & 7;
        float lw = lpw[c], lb = lpb[c];
        wei[(h0 + 0) * C + c] = lw * (m4.x * ilz[h0 + 0] - ilz[NH + h0 + 0]) + lb;
        wei[(h0 + 1) * C + c] = lw * (m4.y * ilz[h0 + 1] - ilz[NH + h0 + 1]) + lb;
        wei[(h0 + 2) * C + c] = lw * (m4.z * ilz[h0 + 2] - ilz[NH + h0 + 2]) + lb;
        wei[(h0 + 3) * C + c] = lw * (m4.w * ilz[h0 + 3] - ilz[NH + h0 + 3]) + lb;
    }
    __syncthreads();

    {   // ctx[j=tid] = wei[h(j),:] . Wv[j,:] + bv[j]
        int h = tid >> 5;
        float a = bv[tid];
        const float* wrow = Wv + (size_t)tid * C;
        const float* wh   = wei + h * C;
        #pragma unroll 8
        for (int c2 = 0; c2 < C; ++c2) a += wh[c2] * wrow[c2];
        ctxs[tid] = a;
    }
    __syncthreads();

    float att = bo[tid];
    {
        const float* wrow = Wo + (size_t)tid * C;
        #pragma unroll 8
        for (int j = 0; j < C; ++j) att += ctxs[j] * wrow[j];
    }
    float upd = mt[(size_t)bn * C + tid] + att;
    upds[tid] = upd;
    __syncthreads();

    #pragma unroll
    for (int r = 0; r < 2; ++r) {
        int k = tid + r * 256;
        float a = b1[k];
        const float* wrow = W1 + (size_t)k * C;
        #pragma unroll 8
        for (int c2 = 0; c2 < C; ++c2) a += upds[c2] * wrow[c2];
        hid[k] = fmaxf(a, 0.f);
    }
    __syncthreads();

    float a = b2[tid];
    const float* wrow = W2 + (size_t)tid * 2 * C;
    #pragma unroll 8
    for (int k = 0; k < 2 * C; ++k) a += hid[k] * wrow[k];
    out[(size_t)bn * C + tid] = upd + a;
}

extern "C" void kernel_launch(void* const* d_in, const int* in_sizes, int n_in,
                              void* d_out, int out_size, void* d_ws, size_t ws_size,
                              hipStream_t stream)
{
    const float* mt  = (const float*)d_in[0];
    const float* pe  = (const float*)d_in[1];
    const float* ltw = (const float*)d_in[2];
    const float* ltb = (const float*)d_in[3];
    const float* lpw = (const float*)d_in[4];
    const float* lpb = (const float*)d_in[5];
    const float* Wq  = (const float*)d_in[6];
    const float* bq  = (const float*)d_in[7];
    const float* Wk  = (const float*)d_in[8];
    const float* bk  = (const float*)d_in[9];
    const float* Wv  = (const float*)d_in[10];
    const float* bv  = (const float*)d_in[11];
    const float* Wo  = (const float*)d_in[12];
    const float* bo  = (const float*)d_in[13];
    const float* W1  = (const float*)d_in[14];
    const float* b1  = (const float*)d_in[15];
    const float* W2  = (const float*)d_in[16];
    const float* b2  = (const float*)d_in[17];

    float* ws   = (float*)d_ws;
    float* outp = (float*)d_out;

    float* gw            = ws + OFF_GW;
    float* Gv            = ws + OFF_G;
    float* Bc            = ws + OFF_BC;
    unsigned short* ptg  = (unsigned short*)(ws + OFF_PTT);
    float* LP            = ws + OFF_LP;
    float* ZP            = ws + OFF_ZP;
    float* Mp            = ws + OFF_MP;

    k1_prep<<<64,   256, 0, stream>>>(mt, ltw, ltb, lpw, lpb, Wq, bq, Wk, bk, gw, Gv, Bc);
    ksweep1<<<256,  256, 0, stream>>>(pe, gw, Gv, Bc, ptg, LP, ZP);
    ksweep2<<<2048, 256, 0, stream>>>(pe, ptg, Mp);
    k5_out <<<64,   256, 0, stream>>>(mt, Mp, LP, ZP, lpw, lpb, Wv, bv, Wo, bo, W1, b1, W2, b2, outp);
}

// Round 13
// 191.335 us; speedup vs baseline: 1.1941x; 1.1941x over previous
//
#include <hip/hip_runtime.h>
#include <math.h>

#define C 256
#define S 4096
#define NH 8
#define NSG 16        // s-groups per bn (256 s each) = Mp partial groups
#define NSTRIP 64     // LP/ZP strips per bn (16 sg x 4 waves)
#define EPS 1e-5f
#define SCALE 0.17677669529663687f   // 1/sqrt(32)

#define PTS 272       // ptT LDS row stride (ushorts)

// workspace layout (float offsets)
#define OFF_GWP 0                  // 64*256*4 uints = 65536
#define OFF_G   65536              // 512
#define OFF_BC  66048              // 512
#define OFF_LP  66560              // 64*8*64 = 32768
#define OFF_ZP  99328              // 32768
#define OFF_MP  132096             // 16*64*256*8 = 2097152

typedef __attribute__((ext_vector_type(8))) short short8;
typedef __attribute__((ext_vector_type(4))) float f32x4;

__device__ __forceinline__ float bf_lo(unsigned int u) {
    return __builtin_bit_cast(float, u << 16);
}
__device__ __forceinline__ float bf_hi(unsigned int u) {
    return __builtin_bit_cast(float, u & 0xffff0000u);
}
__device__ __forceinline__ unsigned int bf_pack(float a, float b) {
    unsigned int ua = (__builtin_bit_cast(unsigned int, a) + 0x8000u) >> 16;
    unsigned int ub = (__builtin_bit_cast(unsigned int, b) + 0x8000u) & 0xffff0000u;
    return ua | ub;
}
__device__ __forceinline__ float bf_round(float a) {   // same rounding as bf_pack lo
    unsigned int u = (__builtin_bit_cast(unsigned int, a) + 0x8000u) & 0xffff0000u;
    return __builtin_bit_cast(float, u);
}

// ---------------------------------------------------------------------------
// K1: LN(mask_tokens) -> q -> fold q into Wk. gw packed bf16 pairs [bn][c][4u].
// Gv accumulated from the SAME bf16-rounded g values kfused will unpack.
// ---------------------------------------------------------------------------
__global__ __launch_bounds__(256) void k1_prep(
    const float* __restrict__ mt, const float* __restrict__ ln_t_w, const float* __restrict__ ln_t_b,
    const float* __restrict__ ln_p_w, const float* __restrict__ ln_p_b,
    const float* __restrict__ Wq, const float* __restrict__ bq,
    const float* __restrict__ Wk, const float* __restrict__ bk,
    unsigned int* __restrict__ gwp, float* __restrict__ Gv, float* __restrict__ Bc)
{
    int bn  = blockIdx.x;
    int tid = threadIdx.x;
    int wid = tid >> 6, lane = tid & 63;
    __shared__ float nt[C];
    __shared__ float qv[C];
    __shared__ float wks[NH][C];
    __shared__ float red[8];

    float x  = mt[bn * C + tid];
    float s1 = x, s2 = x * x;
    #pragma unroll
    for (int off = 32; off; off >>= 1) {
        s1 += __shfl_xor(s1, off);
        s2 += __shfl_xor(s2, off);
    }
    if (lane == 0) { red[wid] = s1; red[4 + wid] = s2; }
    __syncthreads();
    float mu   = (red[0] + red[1] + red[2] + red[3]) * (1.0f / C);
    float msq  = (red[4] + red[5] + red[6] + red[7]) * (1.0f / C);
    float rstd = rsqrtf(msq - mu * mu + EPS);
    nt[tid] = (x - mu) * rstd * ln_t_w[tid] + ln_t_b[tid];
    __syncthreads();

    {   // q[j=tid] = nt . Wq[j,:] + bq[j]
        float acc = bq[tid];
        const float* wrow = Wq + (size_t)tid * C;
        #pragma unroll 8
        for (int c = 0; c < C; ++c) acc += nt[c] * wrow[c];
        qv[tid] = acc;
    }
    __syncthreads();

    int c = tid;
    #pragma unroll
    for (int h = 0; h < NH; ++h) {
        float a = 0.f;
        #pragma unroll 4
        for (int d = 0; d < 32; ++d) a += qv[h * 32 + d] * Wk[(size_t)(h * 32 + d) * C + c];
        wks[h][c] = a * SCALE;
    }
    __syncthreads();

    // gw packed bf16 pairs: gwp[bn][c][pr] = pack(g[2pr], g[2pr+1]), g = lpw*wks
    for (int i = tid; i < C * 4; i += 256) {
        int cc = i >> 2, pr = i & 3;
        float g0 = ln_p_w[cc] * wks[pr * 2][cc];
        float g1 = ln_p_w[cc] * wks[pr * 2 + 1][cc];
        gwp[(size_t)bn * C * 4 + i] = bf_pack(g0, g1);
    }

    {
        int h = tid >> 5, l32 = tid & 31;
        float g = 0.f, bs = 0.f;
        #pragma unroll
        for (int cc = l32; cc < C; cc += 32) {
            float w = wks[h][cc];
            g  += bf_round(ln_p_w[cc] * w);   // match kfused's unpacked value
            bs += ln_p_b[cc] * w;
        }
        float qb = qv[h * 32 + l32] * bk[h * 32 + l32];
        #pragma unroll
        for (int off = 16; off; off >>= 1) {
            g  += __shfl_xor(g, off);
            bs += __shfl_xor(bs, off);
            qb += __shfl_xor(qb, off);
        }
        if (l32 == 0) {
            Gv[bn * NH + h] = g;
            Bc[bn * NH + h] = bs + qb * SCALE;
        }
    }
}

// ---------------------------------------------------------------------------
// KFUSED v5 (MLP-first): grid 1024 = 64 bn x 16 sg(256 s); 4 waves; lane owns
// ONE s (acc = 10 VGPR). Phase1: 16-deep NAMED static load batch (16
// independent global_load_dword in flight; launch_bounds(256,1) gives VGPR
// headroom), g via one broadcast b128/c (bf16x8). In-lane stats -> p -> ptT
// LDS (bf16, [h][s]) + per-wave LP/ZP. ONE barrier. Phase2: MFMA PV over the
// block's own just-read x region (L2/L3-hot), acc direct to Mp.
// ---------------------------------------------------------------------------
__global__ __launch_bounds__(256, 1) void kfused(
    const float* __restrict__ pe, const unsigned int* __restrict__ gwp,
    const float* __restrict__ Gv, const float* __restrict__ Bc,
    float* __restrict__ LP, float* __restrict__ ZP, float* __restrict__ Mp)
{
    int blk = blockIdx.x;                    // 1024
    int swz = (blk & 7) * 128 + (blk >> 3);  // XCD-contiguous chunks
    int bn  = swz >> 4;
    int sg  = swz & 15;
    int tid = threadIdx.x;
    int w = tid >> 6, lane = tid & 63;
    int b = bn >> 3, n = bn & 7;
    const float* xb = pe + ((size_t)(n * 8 + b)) * C * S;
    int sgbase = sg * 256;

    __shared__ uint4 gwt[C];                    // 4 KB: [c] -> bf16 g[0..7]
    __shared__ unsigned short ptT[16 * PTS];    // 8.5 KB

    {
        const uint4* src = reinterpret_cast<const uint4*>(gwp + (size_t)bn * C * 4);
        for (int i = tid; i < C; i += 256) gwt[i] = src[i];
        for (int i = tid; i < 8 * PTS; i += 256) ptT[8 * PTS + i] = 0;  // rows 8-15
    }
    __syncthreads();

    // ---- phase 1: lane owns s = sgbase + tid ----
    {
        const float* xcol = xb + sgbase + tid;
        float sum = 0.f, sq = 0.f;
        float A[NH];
        #pragma unroll
        for (int h = 0; h < NH; ++h) A[h] = 0.f;

        for (int cb = 0; cb < C; cb += 16) {
            float xr[16];
            #pragma unroll
            for (int q = 0; q < 16; ++q)
                xr[q] = xcol[(size_t)(cb + q) * S];   // 16 independent loads
            #pragma unroll
            for (int q = 0; q < 16; ++q) {
                uint4 g = gwt[cb + q];
                float xx = xr[q];
                sum += xx; sq += xx * xx;
                A[0] += bf_lo(g.x) * xx; A[1] += bf_hi(g.x) * xx;
                A[2] += bf_lo(g.y) * xx; A[3] += bf_hi(g.y) * xx;
                A[4] += bf_lo(g.z) * xx; A[5] += bf_hi(g.z) * xx;
                A[6] += bf_lo(g.w) * xx; A[7] += bf_hi(g.w) * xx;
            }
        }

        float mu   = sum * (1.f / C);
        float var  = sq * (1.f / C) - mu * mu;
        float rs   = rsqrtf(var + EPS);
        float murv = mu * rs;

        #pragma unroll
        for (int h = 0; h < NH; ++h) {
            float p = __expf(rs * A[h] - murv * Gv[bn * NH + h] + Bc[bn * NH + h]); // m=0 (validated)
            ptT[h * PTS + tid] = (unsigned short)(bf_pack(p * rs, 0.f) & 0xffffu);
            float l = p, zz = p * murv;
            #pragma unroll
            for (int off = 32; off; off >>= 1) {
                l  += __shfl_xor(l,  off);
                zz += __shfl_xor(zz, off);
            }
            if (lane == 0) {
                int strip = sg * 4 + w;
                LP[(size_t)(bn * NH + h) * NSTRIP + strip] = l;
                ZP[(size_t)(bn * NH + h) * NSTRIP + strip] = zz;
            }
        }
    }
    __syncthreads();

    // ---- phase 2: MFMA PV, A re-read from block's own (cache-hot) region ----
    {
        int mrow = lane & 15;     // A row within tile; D col (= h)
        int kgrp = lane >> 4;     // k block (8 k each)
        float* mp = Mp + (((size_t)sg * 64 + bn) * C) * NH;
        #pragma unroll
        for (int ct = 0; ct < 4; ++ct) {
            int ctile = w * 4 + ct;
            int crow  = ctile * 16 + mrow;
            const float* arow = xb + (size_t)crow * S + sgbase + kgrp * 8;
            f32x4 acc = {0.f, 0.f, 0.f, 0.f};
            #pragma unroll
            for (int kc = 0; kc < 8; ++kc) {
                float4 a0 = *reinterpret_cast<const float4*>(arow + kc * 32);
                float4 a1 = *reinterpret_cast<const float4*>(arow + kc * 32 + 4);
                uint4 ap;
                ap.x = bf_pack(a0.x, a0.y);
                ap.y = bf_pack(a0.z, a0.w);
                ap.z = bf_pack(a1.x, a1.y);
                ap.w = bf_pack(a1.z, a1.w);
                short8 af = __builtin_bit_cast(short8, ap);
                uint4 bp = *reinterpret_cast<const uint4*>(&ptT[mrow * PTS + kc * 32 + kgrp * 8]);
                short8 bfv = __builtin_bit_cast(short8, bp);
                acc = __builtin_amdgcn_mfma_f32_16x16x32_bf16(af, bfv, acc, 0, 0, 0);
            }
            if (mrow < NH) {
                #pragma unroll
                for (int r = 0; r < 4; ++r) {
                    int cl = ctile * 16 + kgrp * 4 + r;
                    mp[cl * NH + mrow] = acc[r];
                }
            }
        }
    }
}

// ---------------------------------------------------------------------------
// KPOST (merged combine+fold+output): per bn: IL/z from 64 strips -> fold 16
// Mp partials -> wei (LDS) -> ctx -> Wo -> residual -> MLP -> out.
// ---------------------------------------------------------------------------
__global__ __launch_bounds__(256) void kpost(
    const float* __restrict__ mt, const float* __restrict__ Mp,
    const float* __restrict__ LP, const float* __restrict__ ZP,
    const float* __restrict__ lpw, const float* __restrict__ lpb,
    const float* __restrict__ Wv, const float* __restrict__ bv,
    const float* __restrict__ Wo, const float* __restrict__ bo,
    const float* __restrict__ W1, const float* __restrict__ b1,
    const float* __restrict__ W2, const float* __restrict__ b2,
    float* __restrict__ out)
{
    int bn  = blockIdx.x;
    int tid = threadIdx.x;
    __shared__ float ilz[2 * NH];
    __shared__ float wei[NH * C];   // [h][c]
    __shared__ float ctxs[C];
    __shared__ float upds[C];
    __shared__ float hid[2 * C];

    if (tid < NH) {
        float L = 0.f, Z = 0.f;
        #pragma unroll 8
        for (int j = 0; j < NSTRIP; ++j) {
            L += LP[(size_t)(bn * NH + tid) * NSTRIP + j];
            Z += ZP[(size_t)(bn * NH + tid) * NSTRIP + j];
        }
        float inv = 1.f / L;
        ilz[tid]      = inv;
        ilz[NH + tid] = Z * inv;
    }
    __syncthreads();

    // fold 16 Mp partials -> wei[h][c]
    for (int v = tid; v < 512; v += 256) {
        int i = v * 4;
        float4 m4 = {0.f, 0.f, 0.f, 0.f};
        #pragma unroll
        for (int sg2 = 0; sg2 < NSG; ++sg2) {
            float4 t = *reinterpret_cast<const float4*>(Mp + ((size_t)sg2 * 64 + bn) * (C * NH) + i);
            m4.x += t.x; m4.y += t.y; m4.z += t.z; m4.w += t.w;
        }
        int c = i >> 3, h0 = i & 7;
        float lw = lpw[c], lb = lpb[c];
        wei[(h0 + 0) * C + c] = lw * (m4.x * ilz[h0 + 0] - ilz[NH + h0 + 0]) + lb;
        wei[(h0 + 1) * C + c] = lw * (m4.y * ilz[h0 + 1] - ilz[NH + h0 + 1]) + lb;
        wei[(h0 + 2) * C + c] = lw * (m4.z * ilz[h0 + 2] - ilz[NH + h0 + 2]) + lb;
        wei[(h0 + 3) * C + c] = lw * (m4.w * ilz[h0 + 3] - ilz[NH + h0 + 3]) + lb;
    }
    __syncthreads();

    {   // ctx[j=tid] = wei[h(j),:] . Wv[j,:] + bv[j]
        int h = tid >> 5;
        float a = bv[tid];
        const float* wrow = Wv + (size_t)tid * C;
        const float* wh   = wei + h * C;
        #pragma unroll 8
        for (int c2 = 0; c2 < C; ++c2) a += wh[c2] * wrow[c2];
        ctxs[tid] = a;
    }
    __syncthreads();

    float att = bo[tid];
    {
        const float* wrow = Wo + (size_t)tid * C;
        #pragma unroll 8
        for (int j = 0; j < C; ++j) att += ctxs[j] * wrow[j];
    }
    float upd = mt[(size_t)bn * C + tid] + att;
    upds[tid] = upd;
    __syncthreads();

    #pragma unroll
    for (int r = 0; r < 2; ++r) {
        int k = tid + r * 256;
        float a = b1[k];
        const float* wrow = W1 + (size_t)k * C;
        #pragma unroll 8
        for (int c2 = 0; c2 < C; ++c2) a += upds[c2] * wrow[c2];
        hid[k] = fmaxf(a, 0.f);
    }
    __syncthreads();

    float a = b2[tid];
    const float* wrow = W2 + (size_t)tid * 2 * C;
    #pragma unroll 8
    for (int k = 0; k < 2 * C; ++k) a += hid[k] * wrow[k];
    out[(size_t)bn * C + tid] = upd + a;
}

extern "C" void kernel_launch(void* const* d_in, const int* in_sizes, int n_in,
                              void* d_out, int out_size, void* d_ws, size_t ws_size,
                              hipStream_t stream)
{
    const float* mt  = (const float*)d_in[0];
    const float* pe  = (const float*)d_in[1];
    const float* ltw = (const float*)d_in[2];
    const float* ltb = (const float*)d_in[3];
    const float* lpw = (const float*)d_in[4];
    const float* lpb = (const float*)d_in[5];
    const float* Wq  = (const float*)d_in[6];
    const float* bq  = (const float*)d_in[7];
    const float* Wk  = (const float*)d_in[8];
    const float* bk  = (const float*)d_in[9];
    const float* Wv  = (const float*)d_in[10];
    const float* bv  = (const float*)d_in[11];
    const float* Wo  = (const float*)d_in[12];
    const float* bo  = (const float*)d_in[13];
    const float* W1  = (const float*)d_in[14];
    const float* b1  = (const float*)d_in[15];
    const float* W2  = (const float*)d_in[16];
    const float* b2  = (const float*)d_in[17];

    float* ws   = (float*)d_ws;
    float* outp = (float*)d_out;

    unsigned int* gwp = (unsigned int*)(ws + OFF_GWP);
    float* Gv         = ws + OFF_G;
    float* Bc         = ws + OFF_BC;
    float* LP         = ws + OFF_LP;
    float* ZP         = ws + OFF_ZP;
    float* Mp         = ws + OFF_MP;

    k1_prep<<<64,   256, 0, stream>>>(mt, ltw, ltb, lpw, lpb, Wq, bq, Wk, bk, gwp, Gv, Bc);
    kfused <<<1024, 256, 0, stream>>>(pe, gwp, Gv, Bc, LP, ZP, Mp);
    kpost  <<<64,   256, 0, stream>>>(mt, Mp, LP, ZP, lpw, lpb, Wv, bv, Wo, bo, W1, b1, W2, b2, outp);
}